// Round 2
// baseline (892.163 us; speedup 1.0000x reference)
//
#include <hip/hip_runtime.h>
#include <math.h>

#define B_ 512
#define T_ 256
#define LOD_ 64
#define LSD_ 128
#define ACT_ 32
#define K_ 15
#define H_ 120

// ---------------------------------------------------------------------------
// Kernel 1: ctrl = relu(act @ w1 + b1) @ w2 + b2   for all B*T rows.
// 80% of total FLOPs, state-independent -> precompute at full occupancy.
// ---------------------------------------------------------------------------
#define ROWS_PER_BLK 32
#define HPAD 124   // padded LDS stride for hidden (120) to avoid bank conflicts

__global__ __launch_bounds__(256) void ctrl_kernel(
    const float* __restrict__ actions, const float* __restrict__ w1,
    const float* __restrict__ b1, const float* __restrict__ w2,
    const float* __restrict__ b2, float* __restrict__ ctrl)
{
  __shared__ float act_s[ROWS_PER_BLK * ACT_];   // 4 KB
  __shared__ float h_s[ROWS_PER_BLK * HPAD];     // ~15.9 KB
  const int tid = threadIdx.x;
  const long long row0 = (long long)blockIdx.x * ROWS_PER_BLK;

  // stage actions tile: 32 rows x 32 = 1024 floats, one float4 per thread
  reinterpret_cast<float4*>(act_s)[tid] =
      reinterpret_cast<const float4*>(actions + row0 * ACT_)[tid];

  const int k  = tid & 127;   // output column (120 used in phase A, 128 in B)
  const int rg = tid >> 7;    // row group: 2 groups x 16 rows

  // w1 column in registers (32 VGPRs)
  float w1r[ACT_];
  float bb = 0.f;
  if (k < H_) {
#pragma unroll
    for (int i = 0; i < ACT_; ++i) w1r[i] = w1[i * H_ + k];
    bb = b1[k];
  }
  __syncthreads();

  // phase A: hidden = relu(act @ w1 + b1)
  if (k < H_) {
    for (int r = 0; r < 16; ++r) {
      const int rr = rg * 16 + r;
      float acc = bb;
#pragma unroll
      for (int i4 = 0; i4 < ACT_ / 4; ++i4) {
        float4 a = reinterpret_cast<const float4*>(act_s + rr * ACT_)[i4];
        acc = fmaf(a.x, w1r[i4 * 4 + 0], acc);
        acc = fmaf(a.y, w1r[i4 * 4 + 1], acc);
        acc = fmaf(a.z, w1r[i4 * 4 + 2], acc);
        acc = fmaf(a.w, w1r[i4 * 4 + 3], acc);
      }
      h_s[rr * HPAD + k] = fmaxf(acc, 0.f);
    }
  }
  __syncthreads();

  // phase B: ctrl = hidden @ w2 + b2  (col k for 16 rows per thread)
  float acc[16];
  const float bo = b2[k];
#pragma unroll
  for (int r = 0; r < 16; ++r) acc[r] = bo;
  for (int j4 = 0; j4 < H_ / 4; ++j4) {
    float wv0 = w2[(j4 * 4 + 0) * LSD_ + k];
    float wv1 = w2[(j4 * 4 + 1) * LSD_ + k];
    float wv2 = w2[(j4 * 4 + 2) * LSD_ + k];
    float wv3 = w2[(j4 * 4 + 3) * LSD_ + k];
#pragma unroll
    for (int r = 0; r < 16; ++r) {
      const int rr = rg * 16 + r;
      float4 h = *reinterpret_cast<const float4*>(h_s + rr * HPAD + j4 * 4);
      acc[r] = fmaf(h.x, wv0, acc[r]);
      acc[r] = fmaf(h.y, wv1, acc[r]);
      acc[r] = fmaf(h.z, wv2, acc[r]);
      acc[r] = fmaf(h.w, wv3, acc[r]);
    }
  }
#pragma unroll
  for (int r = 0; r < 16; ++r) {
    const long long row = row0 + rg * 16 + r;
    ctrl[row * LSD_ + k] = acc[r];
  }
}

// ---------------------------------------------------------------------------
// Kernel 2: the sequential scan. One wave (64 lanes) per batch element.
// Lane l owns state indices l (upper) and l+64 (lower) -> Kalman update,
// covariance, nmu, ncov are lane-local. Only the 15 gating logits need a
// cross-lane reduction (shfl butterfly).
// obs_valid is staged as int32 by the harness (bool -> int path).
// ---------------------------------------------------------------------------
__global__ __launch_bounds__(64) void scan_kernel(
    const float* __restrict__ latent_obs, const float* __restrict__ obs_vars,
    const int* __restrict__ obs_valid,
    const float* __restrict__ initial_mean, const float* __restrict__ initial_cov,
    const float* __restrict__ tm11, const float* __restrict__ tm12,
    const float* __restrict__ tm21, const float* __restrict__ tm22,
    const float* __restrict__ w_coeff, const float* __restrict__ b_coeff,
    const float* __restrict__ ltn, const float* __restrict__ ctrl,
    float* __restrict__ o_pmu, float* __restrict__ o_pcov,
    float* __restrict__ o_prior, float* __restrict__ o_pcov2)
{
  const int b = blockIdx.x;
  const int l = threadIdx.x;

  // per-lane parameter registers
  float t11r[K_], t12r[K_], t21r[K_], t22r[K_], wcu[K_], wcl[K_], bc[K_];
#pragma unroll
  for (int j = 0; j < K_; ++j) {
    t11r[j] = tm11[j * LOD_ + l];
    t12r[j] = tm12[j * LOD_ + l];
    t21r[j] = tm21[j * LOD_ + l];
    t22r[j] = tm22[j * LOD_ + l];
    wcu[j] = w_coeff[l * K_ + j];
    wcl[j] = w_coeff[(LOD_ + l) * K_ + j];
    bc[j] = b_coeff[j];
  }
  // trans noise: elu(x)+1
  float xu = ltn[l], xl = ltn[LOD_ + l];
  float nu_ = (xu > 0.f) ? (xu + 1.f) : expf(xu);
  float nl_ = (xl > 0.f) ? (xl + 1.f) : expf(xl);

  // carry
  float mu_u = initial_mean[(size_t)b * LSD_ + l];
  float mu_l = initial_mean[(size_t)b * LSD_ + LOD_ + l];
  float cu  = initial_cov[(size_t)b * 3 * LOD_ + l];
  float cl_ = initial_cov[(size_t)b * 3 * LOD_ + LOD_ + l];
  float cs  = initial_cov[(size_t)b * 3 * LOD_ + 2 * LOD_ + l];

  const float* lo = latent_obs + (size_t)b * T_ * LOD_;
  const float* ov = obs_vars + (size_t)b * T_ * LOD_;
  const float* ct = ctrl + (size_t)b * T_ * LSD_;
  const int* vp = obs_valid + (size_t)b * T_;

  // prefetch t=0
  float obs_n = lo[l], var_n = ov[l];
  float cta_n = ct[l], ctb_n = ct[LOD_ + l];
  int vld_n = vp[0];

  for (int t = 0; t < T_; ++t) {
    float obs = obs_n, var = var_n, cta = cta_n, ctb = ctb_n;
    bool valid = (vld_n != 0);
    if (t + 1 < T_) {  // prefetch next step (state-independent)
      obs_n = lo[(t + 1) * LOD_ + l];
      var_n = ov[(t + 1) * LOD_ + l];
      cta_n = ct[(t + 1) * LSD_ + l];
      ctb_n = ct[(t + 1) * LSD_ + LOD_ + l];
      vld_n = vp[t + 1];
    }
    // Kalman update (lane-local)
    float rd = 1.0f / (cu + var);
    float qu = cu * rd, ql = cs * rd;
    float res = obs - mu_u;
    float pmu = fmaf(qu, res, mu_u);
    float pml = fmaf(ql, res, mu_l);
    float pcu = (1.f - qu) * cu;
    float pcs = (1.f - qu) * cs;
    float pcl = fmaf(-ql, cs, cl_);
    if (!valid) { pmu = mu_u; pml = mu_l; pcu = cu; pcl = cl_; pcs = cs; }

    // gating logits: 15 dots over 128 dims -> butterfly reduce
    float p[K_];
#pragma unroll
    for (int j = 0; j < K_; ++j) p[j] = fmaf(pml, wcl[j], pmu * wcu[j]);
#pragma unroll
    for (int m = 32; m >= 1; m >>= 1) {
#pragma unroll
      for (int j = 0; j < K_; ++j) p[j] += __shfl_xor(p[j], m, 64);
    }
#pragma unroll
    for (int j = 0; j < K_; ++j) p[j] += bc[j];
    // softmax (redundant per-lane, values tiny)
    float mx = p[0];
#pragma unroll
    for (int j = 1; j < K_; ++j) mx = fmaxf(mx, p[j]);
    float s = 0.f;
#pragma unroll
    for (int j = 0; j < K_; ++j) { p[j] = __expf(p[j] - mx); s += p[j]; }
    float rs = 1.0f / s;
    // transition mixes: 4 x (15 -> per-lane scalar)
    float t11 = 0.f, t12 = 0.f, t21 = 0.f, t22 = 0.f;
#pragma unroll
    for (int j = 0; j < K_; ++j) {
      float c = p[j] * rs;
      t11 = fmaf(c, t11r[j], t11);
      t12 = fmaf(c, t12r[j], t12);
      t21 = fmaf(c, t21r[j], t21);
      t22 = fmaf(c, t22r[j], t22);
    }
    // predict
    float nmu_u = fmaf(t11, pmu, fmaf(t12, pml, cta));
    float nmu_l = fmaf(t21, pmu, fmaf(t22, pml, ctb));
    float ncu = fmaf(t11 * t11, pcu, fmaf(2.f * t11 * t12, pcs, fmaf(t12 * t12, pcl, nu_)));
    float ncl = fmaf(t21 * t21, pcu, fmaf(2.f * t21 * t22, pcs, fmaf(t22 * t22, pcl, nl_)));
    float ncs = fmaf(t11 * t21, pcu, fmaf(t11 * t22 + t12 * t21, pcs, t12 * t22 * pcl));

    // stores (coalesced b32)
    const size_t base = (size_t)b * T_ + t;
    o_pmu[base * LSD_ + l] = pmu;
    o_pmu[base * LSD_ + LOD_ + l] = pml;
    o_prior[base * LSD_ + l] = nmu_u;
    o_prior[base * LSD_ + LOD_ + l] = nmu_l;
    o_pcov[base * 3 * LOD_ + l] = pcu;
    o_pcov[base * 3 * LOD_ + LOD_ + l] = pcl;
    o_pcov[base * 3 * LOD_ + 2 * LOD_ + l] = pcs;
    o_pcov2[base * 3 * LOD_ + l] = pcu;
    o_pcov2[base * 3 * LOD_ + LOD_ + l] = pcl;
    o_pcov2[base * 3 * LOD_ + 2 * LOD_ + l] = pcs;

    mu_u = nmu_u; mu_l = nmu_l; cu = ncu; cl_ = ncl; cs = ncs;
  }
}

// ---------------------------------------------------------------------------
extern "C" void kernel_launch(void* const* d_in, const int* in_sizes, int n_in,
                              void* d_out, int out_size, void* d_ws, size_t ws_size,
                              hipStream_t stream)
{
  const float* latent_obs   = (const float*)d_in[0];
  const float* obs_vars     = (const float*)d_in[1];
  const float* actions      = (const float*)d_in[2];
  const float* initial_mean = (const float*)d_in[3];
  const float* initial_cov  = (const float*)d_in[4];
  const int*   obs_valid    = (const int*)d_in[5];   // bool staged as int32
  const float* tm11 = (const float*)d_in[6];
  const float* tm12 = (const float*)d_in[7];
  const float* tm21 = (const float*)d_in[8];
  const float* tm22 = (const float*)d_in[9];
  const float* w_coeff = (const float*)d_in[10];
  const float* b_coeff = (const float*)d_in[11];
  const float* w1 = (const float*)d_in[12];
  const float* b1 = (const float*)d_in[13];
  const float* w2 = (const float*)d_in[14];
  const float* b2 = (const float*)d_in[15];
  const float* ltn = (const float*)d_in[16];

  float* ctrl = (float*)d_ws;  // B*T*LSD floats = 64 MiB scratch

  float* o_pmu   = (float*)d_out;                         // (B,T,128)
  float* o_pcov  = o_pmu   + (size_t)B_ * T_ * LSD_;      // (B,T,3,64)
  float* o_prior = o_pcov  + (size_t)B_ * T_ * 3 * LOD_;  // (B,T,128)
  float* o_pcov2 = o_prior + (size_t)B_ * T_ * LSD_;      // (B,T,3,64)

  ctrl_kernel<<<(B_ * T_) / ROWS_PER_BLK, 256, 0, stream>>>(
      actions, w1, b1, w2, b2, ctrl);
  scan_kernel<<<B_, 64, 0, stream>>>(
      latent_obs, obs_vars, obs_valid, initial_mean, initial_cov,
      tm11, tm12, tm21, tm22, w_coeff, b_coeff, ltn, ctrl,
      o_pmu, o_pcov, o_prior, o_pcov2);
}

// Round 9
// 878.543 us; speedup vs baseline: 1.0155x; 1.0155x over previous
//
#include <hip/hip_runtime.h>
#include <math.h>

#define B_ 512
#define T_ 256
#define LOD_ 64
#define LSD_ 128
#define ACT_ 32
#define K_ 15
#define H_ 120

// ---------------------------------------------------------------------------
// Kernel 1: ctrl = relu(act @ w1 + b1) @ w2 + b2   for all B*T rows.
// 4x4 register tile per thread: LDS reads per thread 480->120 (phase B),
// FMA:LDS ratio 4 -> 16. w1/w2 read as coalesced float4 (L1/L2-resident).
// ---------------------------------------------------------------------------
#define ROWS_PER_BLK 32
#define HPAD 124   // padded LDS stride for hidden (120)

__global__ __launch_bounds__(256) void ctrl_kernel(
    const float* __restrict__ actions, const float* __restrict__ w1,
    const float* __restrict__ b1, const float* __restrict__ w2,
    const float* __restrict__ b2, float* __restrict__ ctrl)
{
  __shared__ float act_s[ROWS_PER_BLK * ACT_];   // 4 KB
  __shared__ float h_s[ROWS_PER_BLK * HPAD];     // ~15.9 KB
  const int tid = threadIdx.x;
  const long long row0 = (long long)blockIdx.x * ROWS_PER_BLK;

  // stage actions tile: 32 rows x 32 = 1024 floats, one float4 per thread
  reinterpret_cast<float4*>(act_s)[tid] =
      reinterpret_cast<const float4*>(actions + row0 * ACT_)[tid];

  const int cg = tid & 31;   // col group (4 cols)
  const int rg = tid >> 5;   // row group 0..7 (4 rows)
  const int c0 = cg * 4;
  const int r0 = rg * 4;

  __syncthreads();

  // ---- phase A: h = relu(act @ w1 + b1), cols 0..119 (30 col groups) ----
  if (cg < 30) {
    float acc[4][4];
    {
      float4 bb = *reinterpret_cast<const float4*>(b1 + c0);
#pragma unroll
      for (int r = 0; r < 4; ++r) {
        acc[r][0] = bb.x; acc[r][1] = bb.y; acc[r][2] = bb.z; acc[r][3] = bb.w;
      }
    }
#pragma unroll
    for (int i4 = 0; i4 < ACT_ / 4; ++i4) {
      float av[4][4];
#pragma unroll
      for (int r = 0; r < 4; ++r) {
        float4 a = *reinterpret_cast<const float4*>(act_s + (r0 + r) * ACT_ + i4 * 4);
        av[r][0] = a.x; av[r][1] = a.y; av[r][2] = a.z; av[r][3] = a.w;
      }
      float wv[4][4];
#pragma unroll
      for (int i = 0; i < 4; ++i) {
        float4 w = *reinterpret_cast<const float4*>(w1 + (i4 * 4 + i) * H_ + c0);
        wv[i][0] = w.x; wv[i][1] = w.y; wv[i][2] = w.z; wv[i][3] = w.w;
      }
#pragma unroll
      for (int r = 0; r < 4; ++r)
#pragma unroll
        for (int i = 0; i < 4; ++i)
#pragma unroll
          for (int c = 0; c < 4; ++c)
            acc[r][c] = fmaf(av[r][i], wv[i][c], acc[r][c]);
    }
#pragma unroll
    for (int r = 0; r < 4; ++r) {
      float4 o;
      o.x = fmaxf(acc[r][0], 0.f); o.y = fmaxf(acc[r][1], 0.f);
      o.z = fmaxf(acc[r][2], 0.f); o.w = fmaxf(acc[r][3], 0.f);
      *reinterpret_cast<float4*>(h_s + (r0 + r) * HPAD + c0) = o;
    }
  }
  __syncthreads();

  // ---- phase B: ctrl = h @ w2 + b2, cols 0..127 (32 col groups) ----
  float acc[4][4];
  {
    float4 bo = *reinterpret_cast<const float4*>(b2 + c0);
#pragma unroll
    for (int r = 0; r < 4; ++r) {
      acc[r][0] = bo.x; acc[r][1] = bo.y; acc[r][2] = bo.z; acc[r][3] = bo.w;
    }
  }
  for (int j4 = 0; j4 < H_ / 4; ++j4) {
    float hv[4][4];
#pragma unroll
    for (int r = 0; r < 4; ++r) {
      float4 h = *reinterpret_cast<const float4*>(h_s + (r0 + r) * HPAD + j4 * 4);
      hv[r][0] = h.x; hv[r][1] = h.y; hv[r][2] = h.z; hv[r][3] = h.w;
    }
    float wv[4][4];
#pragma unroll
    for (int i = 0; i < 4; ++i) {
      float4 w = *reinterpret_cast<const float4*>(w2 + (j4 * 4 + i) * LSD_ + c0);
      wv[i][0] = w.x; wv[i][1] = w.y; wv[i][2] = w.z; wv[i][3] = w.w;
    }
#pragma unroll
    for (int r = 0; r < 4; ++r)
#pragma unroll
      for (int i = 0; i < 4; ++i)
#pragma unroll
        for (int c = 0; c < 4; ++c)
          acc[r][c] = fmaf(hv[r][i], wv[i][c], acc[r][c]);
  }
#pragma unroll
  for (int r = 0; r < 4; ++r) {
    float4 o;
    o.x = acc[r][0]; o.y = acc[r][1]; o.z = acc[r][2]; o.w = acc[r][3];
    *reinterpret_cast<float4*>(ctrl + (row0 + r0 + r) * LSD_ + c0) = o;
  }
}

// ---------------------------------------------------------------------------
// Kernel 2: the sequential scan. One wave (64 lanes) per batch element.
// __launch_bounds__(64, 1): lift the VGPR cap (R2: VGPR_Count=72 forced the
// ~105 per-lane parameter registers into scratch, reloaded all 256 steps).
// ---------------------------------------------------------------------------
__global__ __launch_bounds__(64, 1) void scan_kernel(
    const float* __restrict__ latent_obs, const float* __restrict__ obs_vars,
    const int* __restrict__ obs_valid,
    const float* __restrict__ initial_mean, const float* __restrict__ initial_cov,
    const float* __restrict__ tm11, const float* __restrict__ tm12,
    const float* __restrict__ tm21, const float* __restrict__ tm22,
    const float* __restrict__ w_coeff, const float* __restrict__ b_coeff,
    const float* __restrict__ ltn, const float* __restrict__ ctrl,
    float* __restrict__ o_pmu, float* __restrict__ o_pcov,
    float* __restrict__ o_prior, float* __restrict__ o_pcov2)
{
  const int b = blockIdx.x;
  const int l = threadIdx.x;

  // per-lane parameter registers (~105 VGPRs — must stay resident)
  float t11r[K_], t12r[K_], t21r[K_], t22r[K_], wcu[K_], wcl[K_], bc[K_];
#pragma unroll
  for (int j = 0; j < K_; ++j) {
    t11r[j] = tm11[j * LOD_ + l];
    t12r[j] = tm12[j * LOD_ + l];
    t21r[j] = tm21[j * LOD_ + l];
    t22r[j] = tm22[j * LOD_ + l];
    wcu[j] = w_coeff[l * K_ + j];
    wcl[j] = w_coeff[(LOD_ + l) * K_ + j];
    bc[j] = b_coeff[j];
  }
  // trans noise: elu(x)+1
  float xu = ltn[l], xl = ltn[LOD_ + l];
  float nu_ = (xu > 0.f) ? (xu + 1.f) : expf(xu);
  float nl_ = (xl > 0.f) ? (xl + 1.f) : expf(xl);

  // carry
  float mu_u = initial_mean[(size_t)b * LSD_ + l];
  float mu_l = initial_mean[(size_t)b * LSD_ + LOD_ + l];
  float cu  = initial_cov[(size_t)b * 3 * LOD_ + l];
  float cl_ = initial_cov[(size_t)b * 3 * LOD_ + LOD_ + l];
  float cs  = initial_cov[(size_t)b * 3 * LOD_ + 2 * LOD_ + l];

  const float* lo = latent_obs + (size_t)b * T_ * LOD_;
  const float* ov = obs_vars + (size_t)b * T_ * LOD_;
  const float* ct = ctrl + (size_t)b * T_ * LSD_;
  const int* vp = obs_valid + (size_t)b * T_;

  // prefetch t=0
  float obs_n = lo[l], var_n = ov[l];
  float cta_n = ct[l], ctb_n = ct[LOD_ + l];
  int vld_n = vp[0];

  for (int t = 0; t < T_; ++t) {
    float obs = obs_n, var = var_n, cta = cta_n, ctb = ctb_n;
    bool valid = (vld_n != 0);
    if (t + 1 < T_) {  // prefetch next step (state-independent)
      obs_n = lo[(t + 1) * LOD_ + l];
      var_n = ov[(t + 1) * LOD_ + l];
      cta_n = ct[(t + 1) * LSD_ + l];
      ctb_n = ct[(t + 1) * LSD_ + LOD_ + l];
      vld_n = vp[t + 1];
    }
    // Kalman update (lane-local)
    float rd = 1.0f / (cu + var);
    float qu = cu * rd, ql = cs * rd;
    float res = obs - mu_u;
    float pmu = fmaf(qu, res, mu_u);
    float pml = fmaf(ql, res, mu_l);
    float pcu = (1.f - qu) * cu;
    float pcs = (1.f - qu) * cs;
    float pcl = fmaf(-ql, cs, cl_);
    if (!valid) { pmu = mu_u; pml = mu_l; pcu = cu; pcl = cl_; pcs = cs; }

    // gating logits: 15 dots over 128 dims -> butterfly reduce
    float p[K_];
#pragma unroll
    for (int j = 0; j < K_; ++j) p[j] = fmaf(pml, wcl[j], pmu * wcu[j]);
#pragma unroll
    for (int m = 32; m >= 1; m >>= 1) {
#pragma unroll
      for (int j = 0; j < K_; ++j) p[j] += __shfl_xor(p[j], m, 64);
    }
#pragma unroll
    for (int j = 0; j < K_; ++j) p[j] += bc[j];
    // softmax (redundant per-lane)
    float mx = p[0];
#pragma unroll
    for (int j = 1; j < K_; ++j) mx = fmaxf(mx, p[j]);
    float s = 0.f;
#pragma unroll
    for (int j = 0; j < K_; ++j) { p[j] = __expf(p[j] - mx); s += p[j]; }
    float rs = 1.0f / s;
    // transition mixes: 4 x (15 -> per-lane scalar)
    float t11 = 0.f, t12 = 0.f, t21 = 0.f, t22 = 0.f;
#pragma unroll
    for (int j = 0; j < K_; ++j) {
      float c = p[j] * rs;
      t11 = fmaf(c, t11r[j], t11);
      t12 = fmaf(c, t12r[j], t12);
      t21 = fmaf(c, t21r[j], t21);
      t22 = fmaf(c, t22r[j], t22);
    }
    // predict
    float nmu_u = fmaf(t11, pmu, fmaf(t12, pml, cta));
    float nmu_l = fmaf(t21, pmu, fmaf(t22, pml, ctb));
    float ncu = fmaf(t11 * t11, pcu, fmaf(2.f * t11 * t12, pcs, fmaf(t12 * t12, pcl, nu_)));
    float ncl = fmaf(t21 * t21, pcu, fmaf(2.f * t21 * t22, pcs, fmaf(t22 * t22, pcl, nl_)));
    float ncs = fmaf(t11 * t21, pcu, fmaf(t11 * t22 + t12 * t21, pcs, t12 * t22 * pcl));

    // stores (coalesced b32)
    const size_t base = (size_t)b * T_ + t;
    o_pmu[base * LSD_ + l] = pmu;
    o_pmu[base * LSD_ + LOD_ + l] = pml;
    o_prior[base * LSD_ + l] = nmu_u;
    o_prior[base * LSD_ + LOD_ + l] = nmu_l;
    o_pcov[base * 3 * LOD_ + l] = pcu;
    o_pcov[base * 3 * LOD_ + LOD_ + l] = pcl;
    o_pcov[base * 3 * LOD_ + 2 * LOD_ + l] = pcs;
    o_pcov2[base * 3 * LOD_ + l] = pcu;
    o_pcov2[base * 3 * LOD_ + LOD_ + l] = pcl;
    o_pcov2[base * 3 * LOD_ + 2 * LOD_ + l] = pcs;

    mu_u = nmu_u; mu_l = nmu_l; cu = ncu; cl_ = ncl; cs = ncs;
  }
}

// ---------------------------------------------------------------------------
extern "C" void kernel_launch(void* const* d_in, const int* in_sizes, int n_in,
                              void* d_out, int out_size, void* d_ws, size_t ws_size,
                              hipStream_t stream)
{
  const float* latent_obs   = (const float*)d_in[0];
  const float* obs_vars     = (const float*)d_in[1];
  const float* actions      = (const float*)d_in[2];
  const float* initial_mean = (const float*)d_in[3];
  const float* initial_cov  = (const float*)d_in[4];
  const int*   obs_valid    = (const int*)d_in[5];   // bool staged as int32
  const float* tm11 = (const float*)d_in[6];
  const float* tm12 = (const float*)d_in[7];
  const float* tm21 = (const float*)d_in[8];
  const float* tm22 = (const float*)d_in[9];
  const float* w_coeff = (const float*)d_in[10];
  const float* b_coeff = (const float*)d_in[11];
  const float* w1 = (const float*)d_in[12];
  const float* b1 = (const float*)d_in[13];
  const float* w2 = (const float*)d_in[14];
  const float* b2 = (const float*)d_in[15];
  const float* ltn = (const float*)d_in[16];

  float* ctrl = (float*)d_ws;  // B*T*LSD floats = 64 MiB scratch

  float* o_pmu   = (float*)d_out;                         // (B,T,128)
  float* o_pcov  = o_pmu   + (size_t)B_ * T_ * LSD_;      // (B,T,3,64)
  float* o_prior = o_pcov  + (size_t)B_ * T_ * 3 * LOD_;  // (B,T,128)
  float* o_pcov2 = o_prior + (size_t)B_ * T_ * LSD_;      // (B,T,3,64)

  ctrl_kernel<<<(B_ * T_) / ROWS_PER_BLK, 256, 0, stream>>>(
      actions, w1, b1, w2, b2, ctrl);
  scan_kernel<<<B_, 64, 0, stream>>>(
      latent_obs, obs_vars, obs_valid, initial_mean, initial_cov,
      tm11, tm12, tm21, tm22, w_coeff, b_coeff, ltn, ctrl,
      o_pmu, o_pcov, o_prior, o_pcov2);
}